// Round 25
// baseline (100.280 us; speedup 1.0000x reference)
//
#include <hip/hip_runtime.h>

#define BB 32
#define CC 768
#define SS 1024
#define LLn 77
#define DD 512
#define LP 80      // padded L for tlc rows / At rows
#define LP2 96     // padded L (K dim) for bf16 MFMA operands, mult of 32
#define QROW 1040  // u16 stride of staged q rows (2080 B; spreads banks)

#define RATIO 0.0751953125f   // 77/1024 exact in fp32
#define IRATIO 13.298701f     // ~1024/77 (window-start computation)

#define CVT_TXT_BLOCKS (BB * LP * DD / 4 / 256)   // 1280
#define CVT_W_BLOCKS ((CC / 32) * (DD / 32))      // 384
#define WT_BLOCKS 14                              // ceil(96*36/256) weight-table entries
#define TG_BLOCKS (BB * 5 * 4)                    // 640
#define QH_BLOCKS (48 * BB)                       // 1536 (16 rows/block, attn-mirrored)
#define ATTN_BLOCKS (48 * BB)                     // 1536

typedef short bf16x8 __attribute__((ext_vector_type(8)));
typedef float f32x4 __attribute__((ext_vector_type(4)));
typedef unsigned short u16;
typedef unsigned int u32;

#define MFMA __builtin_amdgcn_mfma_f32_16x16x32_bf16

__device__ __forceinline__ float bf2f(u32 h16) {
    u32 u = h16 << 16;
    float f; __builtin_memcpy(&f, &u, 4); return f;
}
__device__ __forceinline__ u16 f2bf(float f) {
    u32 u; __builtin_memcpy(&u, &f, 4);
    u += 0x7fffu + ((u >> 16) & 1u);   // RNE
    return (u16)(u >> 16);
}

// aligned window base for l: (stab & ~3) clamped so base+36 <= 1024
__device__ __forceinline__ int win_base(int l) {
    int s_lo = max(0, (int)floorf(((float)l - 0.5f) * IRATIO - 0.5f) - 1);
    int base = s_lo & ~3;
    return min(base, SS - 36);
}

// K0: converts + 36-wide aligned tent-weight table (r22 verbatim).
__global__ __launch_bounds__(256) void k_cvt(const float* __restrict__ text,
                                             const float* __restrict__ Wt,
                                             u16* __restrict__ At,
                                             u16* __restrict__ Wb,
                                             float* __restrict__ wtab_g) {
    __shared__ float tile[32 * 33];
    const int bx = blockIdx.x;
    const int tid = threadIdx.x;
    if (bx < CVT_TXT_BLOCKS) {
        int j = bx * 256 + tid;                    // float4-granular, exact cover
        int row80 = j >> 7, col4 = (j & 127) << 2;
        int b = row80 / LP, l = row80 - b * LP;
        u16 o[4] = {0, 0, 0, 0};
        if (l < LLn) {
            float4 v = *reinterpret_cast<const float4*>(&text[((size_t)b * LLn + l) * DD + col4]);
            o[0] = f2bf(v.x); o[1] = f2bf(v.y); o[2] = f2bf(v.z); o[3] = f2bf(v.w);
        }
        *reinterpret_cast<uint2*>(&At[(size_t)row80 * DD + col4]) = *reinterpret_cast<uint2*>(o);
    } else if (bx < CVT_TXT_BLOCKS + CVT_W_BLOCKS) {
        const int bw = bx - CVT_TXT_BLOCKS;
        const int c0 = (bw % (CC / 32)) * 32, d0 = (bw / (CC / 32)) * 32;
        const int tx = tid & 31, ty = tid >> 5;    // ty 0..7
#pragma unroll
        for (int k = 0; k < 4; ++k) {
            int d = ty + k * 8;
            tile[d * 33 + tx] = Wt[(size_t)(d0 + d) * CC + c0 + tx];
        }
        __syncthreads();
#pragma unroll
        for (int k = 0; k < 4; ++k) {
            int c = ty + k * 8;
            Wb[(size_t)(c0 + c) * DD + d0 + tx] = f2bf(tile[tx * 33 + c]);
        }
    } else {
        // ---- wtab36[l][j] = tent(clamp(src(base(l)+j)) - l), zero outside tent ----
        int idx = (bx - CVT_TXT_BLOCKS - CVT_W_BLOCKS) * 256 + tid;   // 0..3583
        if (idx < 96 * 36) {
            int l = idx / 36, j = idx - l * 36;
            float wgt = 0.f;
            if (l < LLn) {
                int s = win_base(l) + j;           // always in [0, 1023]
                float src = fmaf((float)s + 0.5f, RATIO, -0.5f);
                src = fminf(fmaxf(src, 0.f), 76.f);
                wgt = fmaxf(0.f, 1.f - fabsf(src - (float)l));
            }
            wtab_g[l * 36 + j] = wgt;
        }
    }
}

// K1: fused tgemm (640 blocks) + qh gather with FORCED register ILP-16 q staging
//     (liveness fence + launch_bounds(256,2) so regalloc cannot re-sink the loads).
__global__ __launch_bounds__(256, 2) void k_mid(const float* __restrict__ q,
                                                const u16* __restrict__ At,
                                                const u16* __restrict__ Wb,
                                                const float* __restrict__ wtab_g,
                                                u16* __restrict__ qh,
                                                u16* __restrict__ tc,
                                                u16* __restrict__ tlc) {
    __shared__ __align__(16) u16 qlds[16 * QROW];   // 33280 B staged q rows (bf16)
    const int bx = blockIdx.x;
    const int tid = threadIdx.x;

    if (bx < TG_BLOCKS) {
        // ---- t = text @ W, batch-aligned tiles. bx -> (colgroup, b, tile) ----
        const int cg = bx / 160, mt = bx % 160;
        const int b = mt / 5, tile = mt % 5;
        const int l0 = tile * 16;
        const int w = tid >> 6, lane = tid & 63;
        const int lm = lane & 15, lg = lane >> 4;
        const int c0 = cg * 192 + w * 48;

        f32x4 acc[3];
#pragma unroll
        for (int nt = 0; nt < 3; ++nt) acc[nt] = (f32x4){0.f, 0.f, 0.f, 0.f};

        const u16* ap = At + ((size_t)b * LP + l0 + lm) * DD + lg * 8;
        const u16* bp = Wb + (size_t)(c0 + lm) * DD + lg * 8;
#pragma unroll 4
        for (int ks = 0; ks < 16; ++ks) {
            bf16x8 aq = *reinterpret_cast<const bf16x8*>(ap + ks * 32);
#pragma unroll
            for (int nt = 0; nt < 3; ++nt) {
                bf16x8 bv = *reinterpret_cast<const bf16x8*>(bp + (size_t)nt * 16 * DD + ks * 32);
                acc[nt] = MFMA(aq, bv, acc[nt], 0, 0, 0);
            }
        }

        const int lq = l0 + lg * 4;   // quad start (pad rows produce zero acc)
#pragma unroll
        for (int nt = 0; nt < 3; ++nt) {
            int c = c0 + nt * 16 + lm;
            u16 pk[4];
#pragma unroll
            for (int r = 0; r < 4; ++r) pk[r] = f2bf(acc[nt][r]);
            uint2 pv; __builtin_memcpy(&pv, pk, 8);
            *reinterpret_cast<uint2*>(&tc[((size_t)b * CC + c) * LP2 + lq]) = pv;  // 8B aligned
#pragma unroll
            for (int r = 0; r < 4; ++r)
                tlc[((size_t)b * LP + lq + r) * CC + c] = pk[r];
        }
        if (tile == 4 && lg == 0) {   // zero tc K-pad l=80..95
            uint4 z = {0u, 0u, 0u, 0u};
#pragma unroll
            for (int nt = 0; nt < 3; ++nt) {
                int c = c0 + nt * 16 + lm;
                *reinterpret_cast<uint4*>(&tc[((size_t)b * CC + c) * LP2 + 80]) = z;
                *reinterpret_cast<uint4*>(&tc[((size_t)b * CC + c) * LP2 + 88]) = z;
            }
        }
    } else {
        // ---- qh[b, iBase..+16, l] = (sum_j wtab36[l][j] * q[.., base(l)+j]) * S^-0.5 ----
        const int id = bx - TG_BLOCKS;
        const int o = id >> 3;
        const int b = (id & 7) * 4 + o / 48;       // XCD swizzle (identical to attn)
        const int iBase = (o % 48) * 16;

        // 1. sixteen register loads, FORCED simultaneously live (all issue back-to-back)
        const size_t qBase = ((size_t)b * CC + iBase) * SS + (size_t)(tid << 2);
        f32x4 qv[16];
#pragma unroll
        for (int r = 0; r < 16; ++r)
            qv[r] = *reinterpret_cast<const f32x4*>(&q[qBase + (size_t)r * SS]);
        {   // liveness fence: one value from every row must be live at this point
            float fence = 0.f;
#pragma unroll
            for (int r = 0; r < 16; ++r) fence += qv[r][0];
            asm volatile("" :: "v"(fence));
        }

        // 2. bf16 pack + wave-private linear LDS write (2-way banks, free)
#pragma unroll
        for (int r = 0; r < 16; ++r) {
            u16 pk[4] = {f2bf(qv[r][0]), f2bf(qv[r][1]), f2bf(qv[r][2]), f2bf(qv[r][3])};
            uint2 pv; __builtin_memcpy(&pv, pk, 8);
            *reinterpret_cast<uint2*>(&qlds[r * QROW + (tid << 2)]) = pv;
        }
        __syncthreads();

        // 3. gather: 16*96 = 1536 entries, 6/thread; wtab from global (L1-resident)
#pragma unroll
        for (int k = 0; k < 6; ++k) {
            int idx = tid + (k << 8);
            int r = idx / LP2, l = idx - r * LP2;
            u16 o2 = 0;
            if (l < LLn) {
                const int base = win_base(l);
                const u16* qrow = &qlds[r * QROW + base];
                const f32x4* wp = reinterpret_cast<const f32x4*>(&wtab_g[l * 36]);
                float a = 0.f;
#pragma unroll
                for (int m = 0; m < 9; ++m) {
                    uint2 hv = *reinterpret_cast<const uint2*>(&qrow[m * 4]);
                    f32x4 wv = wp[m];
                    a = fmaf(bf2f(hv.x & 0xffffu), wv[0], a);
                    a = fmaf(bf2f(hv.x >> 16),     wv[1], a);
                    a = fmaf(bf2f(hv.y & 0xffffu), wv[2], a);
                    a = fmaf(bf2f(hv.y >> 16),     wv[3], a);
                }
                o2 = f2bf(a * 0.03125f);   // fold 1024^-0.5
            }
            qh[((size_t)b * CC + iBase + r) * LP2 + l] = o2;
        }
    }
}

// K2: attention + output epilogue (r22 verbatim: XCD swizzle, T14 q-prefetch, NT stores).
__global__ __launch_bounds__(256, 2) void k_attn_out(const u16* __restrict__ qh,
                                                     const u16* __restrict__ tc,
                                                     const u16* __restrict__ tlc,
                                                     const float* __restrict__ q,
                                                     const float* __restrict__ gamma,
                                                     float* __restrict__ out) {
    __shared__ float pmax[4][16];
    __shared__ float psum[4][16];
    __shared__ float us[16 * 80];
    __shared__ __align__(16) char pbuf[4][6400];   // per-wave: P bf16 [16][200] / u f32 [16][81]

    const int id = blockIdx.x;
    const int o = id >> 3;
    const int b = (id & 7) * 4 + o / 48;           // XCD swizzle
    const int iBase = (o % 48) * 16;
    const int tid = threadIdx.x;
    const int w = tid >> 6, lane = tid & 63;
    const int lm = lane & 15, lg = lane >> 4;
    const float g = gamma[0];

    // ---- logits: A = qh rows (3 k-steps), B = tc rows of this wave's j-slice ----
    const u16* qbase = qh + ((size_t)b * CC + iBase + lm) * LP2 + lg * 8;
    bf16x8 aq0 = *reinterpret_cast<const bf16x8*>(qbase);
    bf16x8 aq1 = *reinterpret_cast<const bf16x8*>(qbase + 32);
    bf16x8 aq2 = *reinterpret_cast<const bf16x8*>(qbase + 64);

    f32x4 acc[12];
#pragma unroll
    for (int t = 0; t < 12; ++t) acc[t] = (f32x4){0.f, 0.f, 0.f, 0.f};

    const u16* tcb = tc + ((size_t)b * CC + w * 192 + lm) * LP2 + lg * 8;
#pragma unroll
    for (int t = 0; t < 12; ++t) {
        const u16* p = tcb + (size_t)t * 16 * LP2;
        bf16x8 b0 = *reinterpret_cast<const bf16x8*>(p);
        bf16x8 b1 = *reinterpret_cast<const bf16x8*>(p + 32);
        bf16x8 b2 = *reinterpret_cast<const bf16x8*>(p + 64);
        acc[t] = MFMA(aq0, b0, acc[t], 0, 0, 0);
        acc[t] = MFMA(aq1, b1, acc[t], 0, 0, 0);
        acc[t] = MFMA(aq2, b2, acc[t], 0, 0, 0);
    }

    // ---- T14: prefetch this block's 16 q rows; latency hides under softmax+PV ----
    const size_t qBase = ((size_t)b * CC + iBase) * SS + (size_t)(tid << 2);
    f32x4 qreg[16];
#pragma unroll
    for (int r = 0; r < 16; ++r)
        qreg[r] = *reinterpret_cast<const f32x4*>(&q[qBase + (size_t)r * SS]);

    // ---- softmax (C layout: col = lane&15, row = lg*4 + reg) ----
    float m[4];
#pragma unroll
    for (int r = 0; r < 4; ++r) {
        float mm = acc[0][r];
#pragma unroll
        for (int t = 1; t < 12; ++t) mm = fmaxf(mm, acc[t][r]);
#pragma unroll
        for (int off = 8; off >= 1; off >>= 1) mm = fmaxf(mm, __shfl_xor(mm, off));
        m[r] = mm;
    }
    if (lm == 0) {
#pragma unroll
        for (int r = 0; r < 4; ++r) pmax[w][lg * 4 + r] = m[r];
    }
    __syncthreads();   // A: pmax visible
    float gm[4];
#pragma unroll
    for (int r = 0; r < 4; ++r) {
        int row = lg * 4 + r;
        gm[r] = fmaxf(fmaxf(pmax[0][row], pmax[1][row]), fmaxf(pmax[2][row], pmax[3][row]));
    }
    float s[4] = {0.f, 0.f, 0.f, 0.f};
#pragma unroll
    for (int t = 0; t < 12; ++t) {
#pragma unroll
        for (int r = 0; r < 4; ++r) {
            float e = __expf(acc[t][r] - gm[r]);
            acc[t][r] = e;
            s[r] += e;
        }
    }
#pragma unroll
    for (int r = 0; r < 4; ++r) {
#pragma unroll
        for (int off = 8; off >= 1; off >>= 1) s[r] += __shfl_xor(s[r], off);
    }
    if (lm == 0) {
#pragma unroll
        for (int r = 0; r < 4; ++r) psum[w][lg * 4 + r] = s[r];
    }

    // ---- P -> bf16 into per-wave LDS (wave-private, no barrier) ----
    u16* P = (u16*)pbuf[w];
#pragma unroll
    for (int t = 0; t < 12; ++t) {
#pragma unroll
        for (int r = 0; r < 4; ++r)
            P[(lg * 4 + r) * 200 + t * 16 + lm] = f2bf(acc[t][r]);
    }

    // ---- PV: u[16 x 80] += P[16 x 192] . tlc[192 x 80] ----
    f32x4 u[5];
#pragma unroll
    for (int nt = 0; nt < 5; ++nt) u[nt] = (f32x4){0.f, 0.f, 0.f, 0.f};
    const u16* tb = tlc + ((size_t)b * LP + lm) * CC + w * 192 + lg * 8;
#pragma unroll
    for (int ks = 0; ks < 6; ++ks) {
        bf16x8 pa = *reinterpret_cast<const bf16x8*>(&P[lm * 200 + ks * 32 + lg * 8]);
#pragma unroll
        for (int nt = 0; nt < 5; ++nt) {
            bf16x8 bv = *reinterpret_cast<const bf16x8*>(tb + (size_t)nt * 16 * CC + ks * 32);
            u[nt] = MFMA(pa, bv, u[nt], 0, 0, 0);
        }
    }

    // ---- cross-wave u reduce (alias P buffer; wave-local reuse is ordered) ----
    float* up = (float*)pbuf[w];
#pragma unroll
    for (int nt = 0; nt < 5; ++nt) {
#pragma unroll
        for (int r = 0; r < 4; ++r)
            up[(lg * 4 + r) * 81 + nt * 16 + lm] = u[nt][r];
    }
    __syncthreads();   // B: u partials + psum visible
#pragma unroll
    for (int k = 0; k < 5; ++k) {
        int idx = tid + (k << 8);
        int row = idx / LP, l = idx - row * LP;
        float v = ((float*)pbuf[0])[row * 81 + l] + ((float*)pbuf[1])[row * 81 + l]
                + ((float*)pbuf[2])[row * 81 + l] + ((float*)pbuf[3])[row * 81 + l];
        float denom = psum[0][row] + psum[1][row] + psum[2][row] + psum[3][row];
        us[row * LP + l] = v / denom;
    }
    __syncthreads();   // C: us ready

    // ---- epilogue: out = qreg + gamma * interp(us), nontemporal stores ----
    const int s0 = tid << 2;
    float wgt[4]; int i0k[4], i1x[4];
#pragma unroll
    for (int k = 0; k < 4; ++k) {
        float src = fmaf((float)(s0 + k) + 0.5f, RATIO, -0.5f);
        src = fminf(fmaxf(src, 0.f), 76.f);
        i0k[k] = (int)src;
        wgt[k] = src - (float)i0k[k];
        i1x[k] = (i0k[k] < 76) ? i0k[k] + 1 : 76;
    }
#pragma unroll
    for (int r = 0; r < 16; ++r) {
        const float* ur = &us[r * LP];
        f32x4 ov;
#pragma unroll
        for (int k = 0; k < 4; ++k) {
            float uv = fmaf(1.f - wgt[k], ur[i0k[k]], wgt[k] * ur[i1x[k]]);
            ov[k] = qreg[r][k] + g * uv;
        }
        __builtin_nontemporal_store(ov, reinterpret_cast<f32x4*>(&out[qBase + (size_t)r * SS]));
    }
}

extern "C" void kernel_launch(void* const* d_in, const int* in_sizes, int n_in,
                              void* d_out, int out_size, void* d_ws, size_t ws_size,
                              hipStream_t stream) {
    const float* img   = (const float*)d_in[0];
    const float* text  = (const float*)d_in[1];
    const float* Wt    = (const float*)d_in[2];
    const float* gamma = (const float*)d_in[3];
    float* out = (float*)d_out;
    char* ws = (char*)d_ws;
    u16*   tc_bf  = (u16*)(ws);                   // 32*768*96*2 = 4,718,592
    u16*   tlc_bf = (u16*)(ws + 4718592);         // 32*80*768*2 = 3,932,160
    u16*   qh_bf  = (u16*)(ws + 8650752);         // 32*768*96*2 = 4,718,592
    u16*   At_bf  = (u16*)(ws + 13369344);        // 32*80*512*2 = 2,621,440
    u16*   Wb_bf  = (u16*)(ws + 15990784);        // 768*512*2   =   786,432
    float* wtab_g = (float*)(ws + 16777216);      // 96*36*4     =    13,824  (end 16,791,040)

    k_cvt<<<dim3(CVT_TXT_BLOCKS + CVT_W_BLOCKS + WT_BLOCKS), 256, 0, stream>>>(
        text, Wt, At_bf, Wb_bf, wtab_g);
    k_mid<<<dim3(TG_BLOCKS + QH_BLOCKS), 256, 0, stream>>>(
        img, At_bf, Wb_bf, wtab_g, qh_bf, tc_bf, tlc_bf);
    k_attn_out<<<dim3(ATTN_BLOCKS), 256, 0, stream>>>(qh_bf, tc_bf, tlc_bf, img, gamma, out);
}

// Round 26
// 96.252 us; speedup vs baseline: 1.0418x; 1.0418x over previous
//
#include <hip/hip_runtime.h>

#define BB 32
#define CC 768
#define SS 1024
#define LLn 77
#define DD 512
#define LP 80      // padded L for tlc rows / At rows
#define LP2 96     // padded L (K dim) for bf16 MFMA operands, mult of 32

#define RATIO 0.0751953125f   // 77/1024 exact in fp32
#define IRATIO 13.298701f     // ~1024/77 (window-start computation)

#define CVT_TXT_BLOCKS (BB * LP * DD / 4 / 256)   // 1280
#define CVT_W_BLOCKS ((CC / 32) * (DD / 32))      // 384
#define WT_BLOCKS 14                              // ceil(96*36/256) weight-table entries
#define TG_BLOCKS (BB * 5 * 4)                    // 640
#define QH_BLOCKS (256 * BB)                      // 8192
#define ATTN_BLOCKS (48 * BB)                     // 1536

typedef short bf16x8 __attribute__((ext_vector_type(8)));
typedef float f32x4 __attribute__((ext_vector_type(4)));
typedef unsigned short u16;
typedef unsigned int u32;

#define MFMA __builtin_amdgcn_mfma_f32_16x16x32_bf16

__device__ __forceinline__ u16 f2bf(float f) {
    u32 u; __builtin_memcpy(&u, &f, 4);
    u += 0x7fffu + ((u >> 16) & 1u);   // RNE
    return (u16)(u >> 16);
}

// aligned window base for l: (stab & ~3) clamped so base+36 <= 1024
__device__ __forceinline__ int win_base(int l) {
    int s_lo = max(0, (int)floorf(((float)l - 0.5f) * IRATIO - 0.5f) - 1);
    int base = s_lo & ~3;
    return min(base, SS - 36);
}

// K0: converts + 36-wide aligned tent-weight table.
__global__ __launch_bounds__(256) void k_cvt(const float* __restrict__ text,
                                             const float* __restrict__ Wt,
                                             u16* __restrict__ At,
                                             u16* __restrict__ Wb,
                                             float* __restrict__ wtab_g) {
    __shared__ float tile[32 * 33];
    const int bx = blockIdx.x;
    const int tid = threadIdx.x;
    if (bx < CVT_TXT_BLOCKS) {
        int j = bx * 256 + tid;                    // float4-granular, exact cover
        int row80 = j >> 7, col4 = (j & 127) << 2;
        int b = row80 / LP, l = row80 - b * LP;
        u16 o[4] = {0, 0, 0, 0};
        if (l < LLn) {
            float4 v = *reinterpret_cast<const float4*>(&text[((size_t)b * LLn + l) * DD + col4]);
            o[0] = f2bf(v.x); o[1] = f2bf(v.y); o[2] = f2bf(v.z); o[3] = f2bf(v.w);
        }
        *reinterpret_cast<uint2*>(&At[(size_t)row80 * DD + col4]) = *reinterpret_cast<uint2*>(o);
    } else if (bx < CVT_TXT_BLOCKS + CVT_W_BLOCKS) {
        const int bw = bx - CVT_TXT_BLOCKS;
        const int c0 = (bw % (CC / 32)) * 32, d0 = (bw / (CC / 32)) * 32;
        const int tx = tid & 31, ty = tid >> 5;    // ty 0..7
#pragma unroll
        for (int k = 0; k < 4; ++k) {
            int d = ty + k * 8;
            tile[d * 33 + tx] = Wt[(size_t)(d0 + d) * CC + c0 + tx];
        }
        __syncthreads();
#pragma unroll
        for (int k = 0; k < 4; ++k) {
            int c = ty + k * 8;
            Wb[(size_t)(c0 + c) * DD + d0 + tx] = f2bf(tile[tx * 33 + c]);
        }
    } else {
        // ---- wtab36[l][j] = tent(clamp(src(base(l)+j)) - l), zero outside tent ----
        int idx = (bx - CVT_TXT_BLOCKS - CVT_W_BLOCKS) * 256 + tid;   // 0..3583
        if (idx < 96 * 36) {
            int l = idx / 36, j = idx - l * 36;
            float wgt = 0.f;
            if (l < LLn) {
                int s = win_base(l) + j;           // always in [0, 1023]
                float src = fmaf((float)s + 0.5f, RATIO, -0.5f);
                src = fminf(fmaxf(src, 0.f), 76.f);
                wgt = fmaxf(0.f, 1.f - fabsf(src - (float)l));
            }
            wtab_g[l * 36 + j] = wgt;
        }
    }
}

// K1: fused tgemm (640 blocks) + qh gather with ASYNC global_load_lds q staging (8192 blocks).
__global__ __launch_bounds__(256) void k_mid(const float* __restrict__ q,
                                             const u16* __restrict__ At,
                                             const u16* __restrict__ Wb,
                                             const float* __restrict__ wtab_g,
                                             u16* __restrict__ qh,
                                             u16* __restrict__ tc,
                                             u16* __restrict__ tlc) {
    __shared__ __align__(16) float smem[3 * 1024];   // 12 KB staged q rows
    const int bx = blockIdx.x;
    const int tid = threadIdx.x;

    if (bx < TG_BLOCKS) {
        // ---- t = text @ W, batch-aligned tiles. bx -> (colgroup, b, tile) ----
        const int cg = bx / 160, mt = bx % 160;
        const int b = mt / 5, tile = mt % 5;
        const int l0 = tile * 16;
        const int w = tid >> 6, lane = tid & 63;
        const int lm = lane & 15, lg = lane >> 4;
        const int c0 = cg * 192 + w * 48;

        f32x4 acc[3];
#pragma unroll
        for (int nt = 0; nt < 3; ++nt) acc[nt] = (f32x4){0.f, 0.f, 0.f, 0.f};

        const u16* ap = At + ((size_t)b * LP + l0 + lm) * DD + lg * 8;
        const u16* bp = Wb + (size_t)(c0 + lm) * DD + lg * 8;
#pragma unroll 4
        for (int ks = 0; ks < 16; ++ks) {
            bf16x8 aq = *reinterpret_cast<const bf16x8*>(ap + ks * 32);
#pragma unroll
            for (int nt = 0; nt < 3; ++nt) {
                bf16x8 bv = *reinterpret_cast<const bf16x8*>(bp + (size_t)nt * 16 * DD + ks * 32);
                acc[nt] = MFMA(aq, bv, acc[nt], 0, 0, 0);
            }
        }

        const int lq = l0 + lg * 4;   // quad start (pad rows produce zero acc)
#pragma unroll
        for (int nt = 0; nt < 3; ++nt) {
            int c = c0 + nt * 16 + lm;
            u16 pk[4];
#pragma unroll
            for (int r = 0; r < 4; ++r) pk[r] = f2bf(acc[nt][r]);
            uint2 pv; __builtin_memcpy(&pv, pk, 8);
            *reinterpret_cast<uint2*>(&tc[((size_t)b * CC + c) * LP2 + lq]) = pv;  // 8B aligned
#pragma unroll
            for (int r = 0; r < 4; ++r)
                tlc[((size_t)b * LP + lq + r) * CC + c] = pk[r];
        }
        if (tile == 4 && lg == 0) {   // zero tc K-pad l=80..95
            uint4 z = {0u, 0u, 0u, 0u};
#pragma unroll
            for (int nt = 0; nt < 3; ++nt) {
                int c = c0 + nt * 16 + lm;
                *reinterpret_cast<uint4*>(&tc[((size_t)b * CC + c) * LP2 + 80]) = z;
                *reinterpret_cast<uint4*>(&tc[((size_t)b * CC + c) * LP2 + 88]) = z;
            }
        }
    } else {
        // ---- qh[b,c,l] = (sum_j wtab36[l][j] * q[b,c,base(l)+j]) * S^-0.5 ----
        // ASYNC stage: 3 fire-and-forget global_load_lds per thread (no VGPR dest,
        // cannot be re-sunk by regalloc; all 3 overlap in one latency window).
        const int bxq = bx - TG_BLOCKS;
        const int b = bxq >> 8;
        const int c0 = (bxq & 255) * 3;
        const int w = tid >> 6, lane = tid & 63;
        const int off = (w << 8) + (lane << 2);    // wave-linear: byte = w*1024 + lane*16
#pragma unroll
        for (int r = 0; r < 3; ++r) {
            const float* gp = &q[((size_t)b * CC + c0 + r) * SS + off];
            float* lp = &smem[r * 1024 + off];
            __builtin_amdgcn_global_load_lds(
                (const __attribute__((address_space(1))) void*)gp,
                (__attribute__((address_space(3))) void*)lp, 16, 0, 0);
        }
        __syncthreads();   // drains vmcnt (barrier semantics) -> smem ready

        // gather: LDS q + global wtab (13.8 KB, L1-resident)
#pragma unroll
        for (int k = 0; k < 2; ++k) {
            int idx = tid + (k << 8);
            if (idx >= 3 * LP2) break;
            int r = idx / LP2, l = idx - r * LP2;
            u16 o = 0;
            if (l < LLn) {
                const int base = win_base(l);
                const f32x4* qp = reinterpret_cast<const f32x4*>(&smem[r * 1024 + base]);
                const f32x4* wp = reinterpret_cast<const f32x4*>(&wtab_g[l * 36]);
                f32x4 qv[9], wv[9];
#pragma unroll
                for (int j = 0; j < 9; ++j) { qv[j] = qp[j]; wv[j] = wp[j]; }
                float a = 0.f;
#pragma unroll
                for (int j = 0; j < 9; ++j) {
#pragma unroll
                    for (int e = 0; e < 4; ++e)
                        a = fmaf(qv[j][e], wv[j][e], a);
                }
                o = f2bf(a * 0.03125f);   // fold 1024^-0.5
            }
            qh[((size_t)b * CC + c0 + r) * LP2 + l] = o;
        }
    }
}

// K2: attention + output epilogue (XCD swizzle, T14 q-prefetch, NT stores).
__global__ __launch_bounds__(256, 2) void k_attn_out(const u16* __restrict__ qh,
                                                     const u16* __restrict__ tc,
                                                     const u16* __restrict__ tlc,
                                                     const float* __restrict__ q,
                                                     const float* __restrict__ gamma,
                                                     float* __restrict__ out) {
    __shared__ float pmax[4][16];
    __shared__ float psum[4][16];
    __shared__ float us[16 * 80];
    __shared__ __align__(16) char pbuf[4][6400];   // per-wave: P bf16 [16][200] / u f32 [16][81]

    const int id = blockIdx.x;
    const int o = id >> 3;
    const int b = (id & 7) * 4 + o / 48;           // XCD swizzle
    const int iBase = (o % 48) * 16;
    const int tid = threadIdx.x;
    const int w = tid >> 6, lane = tid & 63;
    const int lm = lane & 15, lg = lane >> 4;
    const float g = gamma[0];

    // ---- logits: A = qh rows (3 k-steps), B = tc rows of this wave's j-slice ----
    const u16* qbase = qh + ((size_t)b * CC + iBase + lm) * LP2 + lg * 8;
    bf16x8 aq0 = *reinterpret_cast<const bf16x8*>(qbase);
    bf16x8 aq1 = *reinterpret_cast<const bf16x8*>(qbase + 32);
    bf16x8 aq2 = *reinterpret_cast<const bf16x8*>(qbase + 64);

    f32x4 acc[12];
#pragma unroll
    for (int t = 0; t < 12; ++t) acc[t] = (f32x4){0.f, 0.f, 0.f, 0.f};

    const u16* tcb = tc + ((size_t)b * CC + w * 192 + lm) * LP2 + lg * 8;
#pragma unroll
    for (int t = 0; t < 12; ++t) {
        const u16* p = tcb + (size_t)t * 16 * LP2;
        bf16x8 b0 = *reinterpret_cast<const bf16x8*>(p);
        bf16x8 b1 = *reinterpret_cast<const bf16x8*>(p + 32);
        bf16x8 b2 = *reinterpret_cast<const bf16x8*>(p + 64);
        acc[t] = MFMA(aq0, b0, acc[t], 0, 0, 0);
        acc[t] = MFMA(aq1, b1, acc[t], 0, 0, 0);
        acc[t] = MFMA(aq2, b2, acc[t], 0, 0, 0);
    }

    // ---- T14: prefetch this block's 16 q rows; latency hides under softmax+PV ----
    const size_t qBase = ((size_t)b * CC + iBase) * SS + (size_t)(tid << 2);
    f32x4 qreg[16];
#pragma unroll
    for (int r = 0; r < 16; ++r)
        qreg[r] = *reinterpret_cast<const f32x4*>(&q[qBase + (size_t)r * SS]);

    // ---- softmax (C layout: col = lane&15, row = lg*4 + reg) ----
    float m[4];
#pragma unroll
    for (int r = 0; r < 4; ++r) {
        float mm = acc[0][r];
#pragma unroll
        for (int t = 1; t < 12; ++t) mm = fmaxf(mm, acc[t][r]);
#pragma unroll
        for (int off = 8; off >= 1; off >>= 1) mm = fmaxf(mm, __shfl_xor(mm, off));
        m[r] = mm;
    }
    if (lm == 0) {
#pragma unroll
        for (int r = 0; r < 4; ++r) pmax[w][lg * 4 + r] = m[r];
    }
    __syncthreads();   // A: pmax visible
    float gm[4];
#pragma unroll
    for (int r = 0; r < 4; ++r) {
        int row = lg * 4 + r;
        gm[r] = fmaxf(fmaxf(pmax[0][row], pmax[1][row]), fmaxf(pmax[2][row], pmax[3][row]));
    }
    float s[4] = {0.f, 0.f, 0.f, 0.f};
#pragma unroll
    for (int t = 0; t < 12; ++t) {
#pragma unroll
        for (int r = 0; r < 4; ++r) {
            float e = __expf(acc[t][r] - gm[r]);
            acc[t][r] = e;
            s[r] += e;
        }
    }
#pragma unroll
    for (int r = 0; r < 4; ++r) {
#pragma unroll
        for (int off = 8; off >= 1; off >>= 1) s[r] += __shfl_xor(s[r], off);
    }
    if (lm == 0) {
#pragma unroll
        for (int r = 0; r < 4; ++r) psum[w][lg * 4 + r] = s[r];
    }

    // ---- P -> bf16 into per-wave LDS (wave-private, no barrier) ----
    u16* P = (u16*)pbuf[w];
#pragma unroll
    for (int t = 0; t < 12; ++t) {
#pragma unroll
        for (int r = 0; r < 4; ++r)
            P[(lg * 4 + r) * 200 + t * 16 + lm] = f2bf(acc[t][r]);
    }

    // ---- PV: u[16 x 80] += P[16 x 192] . tlc[192 x 80] ----
    f32x4 u[5];
#pragma unroll
    for (int nt = 0; nt < 5; ++nt) u[nt] = (f32x4){0.f, 0.f, 0.f, 0.f};
    const u16* tb = tlc + ((size_t)b * LP + lm) * CC + w * 192 + lg * 8;
#pragma unroll
    for (int ks = 0; ks < 6; ++ks) {
        bf16x8 pa = *reinterpret_cast<const bf16x8*>(&P[lm * 200 + ks * 32 + lg * 8]);
#pragma unroll
        for (int nt = 0; nt < 5; ++nt) {
            bf16x8 bv = *reinterpret_cast<const bf16x8*>(tb + (size_t)nt * 16 * CC + ks * 32);
            u[nt] = MFMA(pa, bv, u[nt], 0, 0, 0);
        }
    }

    // ---- cross-wave u reduce (alias P buffer; wave-local reuse is ordered) ----
    float* up = (float*)pbuf[w];
#pragma unroll
    for (int nt = 0; nt < 5; ++nt) {
#pragma unroll
        for (int r = 0; r < 4; ++r)
            up[(lg * 4 + r) * 81 + nt * 16 + lm] = u[nt][r];
    }
    __syncthreads();   // B: u partials + psum visible
#pragma unroll
    for (int k = 0; k < 5; ++k) {
        int idx = tid + (k << 8);
        int row = idx / LP, l = idx - row * LP;
        float v = ((float*)pbuf[0])[row * 81 + l] + ((float*)pbuf[1])[row * 81 + l]
                + ((float*)pbuf[2])[row * 81 + l] + ((float*)pbuf[3])[row * 81 + l];
        float denom = psum[0][row] + psum[1][row] + psum[2][row] + psum[3][row];
        us[row * LP + l] = v / denom;
    }
    __syncthreads();   // C: us ready

    // ---- epilogue: out = qreg + gamma * interp(us), nontemporal stores ----
    const int s0 = tid << 2;
    float wgt[4]; int i0k[4], i1x[4];
#pragma unroll
    for (int k = 0; k < 4; ++k) {
        float src = fmaf((float)(s0 + k) + 0.5f, RATIO, -0.5f);
        src = fminf(fmaxf(src, 0.f), 76.f);
        i0k[k] = (int)src;
        wgt[k] = src - (float)i0k[k];
        i1x[k] = (i0k[k] < 76) ? i0k[k] + 1 : 76;
    }
#pragma unroll
    for (int r = 0; r < 16; ++r) {
        const float* ur = &us[r * LP];
        f32x4 ov;
#pragma unroll
        for (int k = 0; k < 4; ++k) {
            float uv = fmaf(1.f - wgt[k], ur[i0k[k]], wgt[k] * ur[i1x[k]]);
            ov[k] = qreg[r][k] + g * uv;
        }
        __builtin_nontemporal_store(ov, reinterpret_cast<f32x4*>(&out[qBase + (size_t)r * SS]));
    }
}

extern "C" void kernel_launch(void* const* d_in, const int* in_sizes, int n_in,
                              void* d_out, int out_size, void* d_ws, size_t ws_size,
                              hipStream_t stream) {
    const float* img   = (const float*)d_in[0];
    const float* text  = (const float*)d_in[1];
    const float* Wt    = (const float*)d_in[2];
    const float* gamma = (const float*)d_in[3];
    float* out = (float*)d_out;
    char* ws = (char*)d_ws;
    u16*   tc_bf  = (u16*)(ws);                   // 32*768*96*2 = 4,718,592
    u16*   tlc_bf = (u16*)(ws + 4718592);         // 32*80*768*2 = 3,932,160
    u16*   qh_bf  = (u16*)(ws + 8650752);         // 32*768*96*2 = 4,718,592
    u16*   At_bf  = (u16*)(ws + 13369344);        // 32*80*512*2 = 2,621,440
    u16*   Wb_bf  = (u16*)(ws + 15990784);        // 768*512*2   =   786,432
    float* wtab_g = (float*)(ws + 16777216);      // 96*36*4     =    13,824  (end 16,791,040)

    k_cvt<<<dim3(CVT_TXT_BLOCKS + CVT_W_BLOCKS + WT_BLOCKS), 256, 0, stream>>>(
        text, Wt, At_bf, Wb_bf, wtab_g);
    k_mid<<<dim3(TG_BLOCKS + QH_BLOCKS), 256, 0, stream>>>(
        img, At_bf, Wb_bf, wtab_g, qh_bf, tc_bf, tlc_bf);
    k_attn_out<<<dim3(ATTN_BLOCKS), 256, 0, stream>>>(qh_bf, tc_bf, tlc_bf, img, gamma, out);
}